// Round 3
// baseline (1717.188 us; speedup 1.0000x reference)
//
#include <hip/hip_runtime.h>
#include <hip/hip_bf16.h>

#define NA 100000
#define NE 800000
#define FDIM 133
#define KIN 192          // 133 padded to 3*64
#define H 256
#define NMOL 4096

typedef __attribute__((ext_vector_type(8))) short s16x8;
typedef __attribute__((ext_vector_type(4))) float f32x4;

__device__ __forceinline__ float bf2f(unsigned short h) {
    unsigned u = ((unsigned)h) << 16;
    return __builtin_bit_cast(float, u);
}
__device__ __forceinline__ unsigned short f2bf(float f) {
    unsigned u = __builtin_bit_cast(unsigned, f);
    u = u + 0x7FFFu + ((u >> 16) & 1u);
    return (unsigned short)(u >> 16);
}

// element offset (in shorts) of 16B group g (0..7) of row (0..127) in a [128][64] bf16 tile,
// XOR-swizzled: staging places global group g at slot g^(row&7); read at swz(row,g) recovers it.
__device__ __forceinline__ int swz(int row, int g) {
    return row * 64 + ((g ^ (row & 7)) << 3);
}

__device__ __forceinline__ void gload_lds16(const void* g, void* l) {
    __builtin_amdgcn_global_load_lds((const __attribute__((address_space(1))) unsigned int*)g,
                                     (__attribute__((address_space(3))) unsigned int*)l, 16, 0, 0);
}

// ============ hidden GEMM: C[M][256] = A'[M][256] * BT[256][256]^T + bias, fused BN stats ============
// AFFINE: A' = relu(A*sc+sh) applied at A-frag build (BN+ReLU fold)
// always: column stats of fp32 output -> atomics -> last-block finalize writes scOut/shOut
template<bool AFFINE>
__global__ __launch_bounds__(256) void gemmH_k(
    const unsigned short* __restrict__ A,
    const unsigned short* __restrict__ BT,
    const float* __restrict__ bias,
    const float* __restrict__ aSc, const float* __restrict__ aSh,
    unsigned short* __restrict__ C,
    float* __restrict__ stSum, float* __restrict__ stSq, int* __restrict__ ticket,
    const float* __restrict__ g, const float* __restrict__ be,
    float* __restrict__ scOut, float* __restrict__ shOut,
    int M)
{
    __shared__ short lsA2[2][128 * 64];
    __shared__ short lsB2[2][128 * 64];
    __shared__ float lsSc[256], lsSh[256];
    __shared__ float lsS[128], lsQ[128];
    __shared__ int lsLast;

    const int t = threadIdx.x;
    const int m0 = blockIdx.y * 128;
    const int n0 = blockIdx.x * 128;

    if (t < 128) { lsS[t] = 0.f; lsQ[t] = 0.f; }
    if (AFFINE) { lsSc[t] = aSc[t]; lsSh[t] = aSh[t]; }

    const int lane = t & 63;
    const int wid = t >> 6;
    const int wm = wid >> 1, wn = wid & 1;
    const int fr = lane & 15, fg = lane >> 4;

    // direct-to-LDS staging: linear LDS dest, inverse-swizzled global source (rule: both-sides-or-neither)
    auto stage = [&](int kc, int ab) {
        #pragma unroll
        for (int c = 0; c < 4; ++c) {
            int slot = c * 256 + t;          // 16B slots, wave-linear
            int row = slot >> 3, gs = slot & 7;
            int coff = kc * 64 + ((gs ^ (row & 7)) << 3);
            if (m0 + row < M)
                gload_lds16(A + (size_t)(m0 + row) * 256 + coff, &lsA2[ab][slot * 8]);
            gload_lds16(BT + (size_t)(n0 + row) * 256 + coff, &lsB2[ab][slot * 8]);
        }
    };

    f32x4 acc[4][4];
    #pragma unroll
    for (int i = 0; i < 4; i++)
        #pragma unroll
        for (int j = 0; j < 4; j++)
            acc[i][j] = f32x4{0.f, 0.f, 0.f, 0.f};

    stage(0, 0);
    __syncthreads();                          // barrier drain waits vmcnt(0)

    for (int kc = 0; kc < 4; ++kc) {
        int ab = kc & 1;
        if (kc < 3) stage(kc + 1, ab ^ 1);    // next chunk in flight across this chunk's MFMAs
        #pragma unroll
        for (int ks = 0; ks < 2; ++ks) {
            s16x8 af[4], bg[4];
            #pragma unroll
            for (int mi = 0; mi < 4; ++mi)
                af[mi] = *(const s16x8*)&lsA2[ab][swz(wm * 64 + mi * 16 + fr, ks * 4 + fg)];
            #pragma unroll
            for (int ni = 0; ni < 4; ++ni)
                bg[ni] = *(const s16x8*)&lsB2[ab][swz(wn * 64 + ni * 16 + fr, ks * 4 + fg)];
            if (AFFINE) {
                int kb = kc * 64 + ks * 32 + fg * 8;
                f32x4 sA = *(const f32x4*)&lsSc[kb], sB = *(const f32x4*)&lsSc[kb + 4];
                f32x4 hA = *(const f32x4*)&lsSh[kb], hB = *(const f32x4*)&lsSh[kb + 4];
                #pragma unroll
                for (int mi = 0; mi < 4; ++mi) {
                    s16x8 v = af[mi];
                    #pragma unroll
                    for (int e = 0; e < 4; ++e) {
                        float f0 = fmaxf(bf2f((unsigned short)v[e]) * sA[e] + hA[e], 0.f);
                        float f1 = fmaxf(bf2f((unsigned short)v[e + 4]) * sB[e] + hB[e], 0.f);
                        v[e] = (short)f2bf(f0);
                        v[e + 4] = (short)f2bf(f1);
                    }
                    af[mi] = v;
                }
            }
            #pragma unroll
            for (int mi = 0; mi < 4; ++mi)
                #pragma unroll
                for (int ni = 0; ni < 4; ++ni)
                    acc[mi][ni] = __builtin_amdgcn_mfma_f32_16x16x32_bf16(
                        af[mi], bg[ni], acc[mi][ni], 0, 0, 0);
        }
        __syncthreads();
    }

    // epilogue: C/D layout col=lane&15, row=(lane>>4)*4+reg
    #pragma unroll
    for (int ni = 0; ni < 4; ++ni) {
        int lcol = wn * 64 + ni * 16 + fr;
        float bc = bias[n0 + lcol];
        float cs = 0.f, cq = 0.f;
        #pragma unroll
        for (int mi = 0; mi < 4; ++mi) {
            #pragma unroll
            for (int r = 0; r < 4; ++r) {
                int row = m0 + wm * 64 + mi * 16 + fg * 4 + r;
                if (row < M) {
                    float v = acc[mi][ni][r] + bc;
                    cs += v; cq += v * v;
                    C[(size_t)row * H + n0 + lcol] = f2bf(v);
                }
            }
        }
        atomicAdd(&lsS[lcol], cs);
        atomicAdd(&lsQ[lcol], cq);
    }
    __syncthreads();
    if (t < 128) {
        atomicAdd(&stSum[n0 + t], lsS[t]);
        atomicAdd(&stSq[n0 + t], lsQ[t]);
    }
    __threadfence();
    __syncthreads();
    if (t == 0)
        lsLast = (atomicAdd(ticket, 1) == (int)(gridDim.x * gridDim.y) - 1) ? 1 : 0;
    __syncthreads();
    if (lsLast) {
        __threadfence();
        if (t < 256) {
            float mean = stSum[t] * (1.0f / (float)M);
            float var = stSq[t] * (1.0f / (float)M) - mean * mean;
            float sc = g[t] * rsqrtf(var + 1e-5f);
            scOut[t] = sc;
            shOut[t] = be[t] - mean * sc;
            stSum[t] = 0.f; stSq[t] = 0.f;   // ready for next stats pass
        }
        if (t == 0) *ticket = 0;
    }
}

// ============ input GEMM: X = relu(f_atoms[M][133] @ Win + b), reg-staged (f32->bf16 convert) ============
__global__ __launch_bounds__(256) void gemmI_k(
    const float* __restrict__ Af,
    const unsigned short* __restrict__ BT,
    const float* __restrict__ bias,
    unsigned short* __restrict__ C, int M)
{
    __shared__ short lsA[128 * 64];
    __shared__ short lsB[128 * 64];

    const int t = threadIdx.x;
    const int m0 = blockIdx.y * 128;
    const int n0 = blockIdx.x * 128;
    const int sr = t >> 3, sg = t & 7;
    const int lane = t & 63, wid = t >> 6;
    const int wm = wid >> 1, wn = wid & 1;
    const int fr = lane & 15, fg = lane >> 4;

    f32x4 acc[4][4];
    #pragma unroll
    for (int i = 0; i < 4; i++)
        #pragma unroll
        for (int j = 0; j < 4; j++)
            acc[i][j] = f32x4{0.f, 0.f, 0.f, 0.f};

    s16x8 ra[4], rb[4];
    auto loadRegs = [&](int kc) {
        const int k0 = kc * 64;
        #pragma unroll
        for (int p = 0; p < 4; ++p) {
            int r = p * 32 + sr;
            int ga = m0 + r;
            s16x8 v;
            #pragma unroll
            for (int e = 0; e < 8; ++e) {
                int k = k0 + sg * 8 + e;
                float f = (ga < M && k < FDIM) ? Af[(size_t)ga * FDIM + k] : 0.f;
                v[e] = (short)f2bf(f);
            }
            ra[p] = v;
            rb[p] = *(const s16x8*)(BT + (size_t)(n0 + r) * KIN + k0 + sg * 8);
        }
    };
    auto writeLds = [&]() {
        #pragma unroll
        for (int p = 0; p < 4; ++p) {
            int r = p * 32 + sr;
            *(s16x8*)&lsA[swz(r, sg)] = ra[p];
            *(s16x8*)&lsB[swz(r, sg)] = rb[p];
        }
    };

    loadRegs(0);
    for (int kc = 0; kc < 3; ++kc) {
        writeLds();
        __syncthreads();
        if (kc + 1 < 3) loadRegs(kc + 1);
        #pragma unroll
        for (int ks = 0; ks < 2; ++ks) {
            s16x8 af[4], bg[4];
            #pragma unroll
            for (int mi = 0; mi < 4; ++mi)
                af[mi] = *(const s16x8*)&lsA[swz(wm * 64 + mi * 16 + fr, ks * 4 + fg)];
            #pragma unroll
            for (int ni = 0; ni < 4; ++ni)
                bg[ni] = *(const s16x8*)&lsB[swz(wn * 64 + ni * 16 + fr, ks * 4 + fg)];
            #pragma unroll
            for (int mi = 0; mi < 4; ++mi)
                #pragma unroll
                for (int ni = 0; ni < 4; ++ni)
                    acc[mi][ni] = __builtin_amdgcn_mfma_f32_16x16x32_bf16(
                        af[mi], bg[ni], acc[mi][ni], 0, 0, 0);
        }
        __syncthreads();
    }

    #pragma unroll
    for (int ni = 0; ni < 4; ++ni) {
        float bc = bias[n0 + wn * 64 + ni * 16 + fr];
        #pragma unroll
        for (int mi = 0; mi < 4; ++mi) {
            #pragma unroll
            for (int r = 0; r < 4; ++r) {
                int row = m0 + wm * 64 + mi * 16 + fg * 4 + r;
                if (row < M) {
                    float v = fmaxf(acc[mi][ni][r] + bc, 0.f);
                    C[(size_t)row * H + n0 + wn * 64 + ni * 16 + fr] = f2bf(v);
                }
            }
        }
    }
}

// ---------------- init ----------------
__global__ void zero_k(int* __restrict__ counts, float* __restrict__ st,
                       int* __restrict__ ticket, int* __restrict__ rowstart) {
    int i = blockIdx.x * 256 + threadIdx.x;
    if (i < NA) counts[i] = 0;
    if (blockIdx.x == 0) {
        st[threadIdx.x] = 0.f; st[threadIdx.x + 256] = 0.f;
        if (threadIdx.x == 0) { *ticket = 0; rowstart[NA] = NE; }
    }
}

// ---------------- CSR build ----------------
__global__ void hist_k(const int* __restrict__ dst, int* __restrict__ counts) {
    int e = blockIdx.x * 256 + threadIdx.x;
    if (e < NE) atomicAdd(&counts[dst[e]], 1);
}
__global__ void scan1_k(const int* __restrict__ counts, int* __restrict__ excl, int* __restrict__ bsum) {
    __shared__ int sd[256];
    int i = blockIdx.x * 256 + threadIdx.x;
    int c = (i < NA) ? counts[i] : 0;
    sd[threadIdx.x] = c;
    __syncthreads();
    for (int off = 1; off < 256; off <<= 1) {
        int v = (threadIdx.x >= off) ? sd[threadIdx.x - off] : 0;
        __syncthreads();
        sd[threadIdx.x] += v;
        __syncthreads();
    }
    if (i < NA) excl[i] = sd[threadIdx.x] - c;
    if (threadIdx.x == 255) bsum[blockIdx.x] = sd[255];
}
__global__ void scan2_k(int* __restrict__ bsum, int nb) {
    __shared__ int sd[512];
    int t = threadIdx.x;
    int v = (t < nb) ? bsum[t] : 0;
    sd[t] = v;
    __syncthreads();
    for (int off = 1; off < 512; off <<= 1) {
        int u = (t >= off) ? sd[t - off] : 0;
        __syncthreads();
        sd[t] += u;
        __syncthreads();
    }
    if (t < nb) bsum[t] = sd[t] - v;
}
__global__ void scan3_k(int* __restrict__ rowstart, const int* __restrict__ bsum, int* __restrict__ cursor) {
    int i = blockIdx.x * 256 + threadIdx.x;
    if (i < NA) {
        int v = rowstart[i] + bsum[blockIdx.x];
        rowstart[i] = v;
        cursor[i] = v;
    }
}
__global__ void fill_k(const int* __restrict__ src, const int* __restrict__ dstArr,
                       int* __restrict__ cursor, int* __restrict__ esrc) {
    int e = blockIdx.x * 256 + threadIdx.x;
    if (e < NE) {
        int d = dstArr[e];
        int pos = atomicAdd(&cursor[d], 1);
        esrc[pos] = src[e];
    }
}

// ---------------- neighbor aggregation ----------------
// one row/wave; halves walk contiguous sub-ranges, 4 gathers in flight; shfl merge
template<bool AFF>
__global__ __launch_bounds__(256) void agg_k(const unsigned short* __restrict__ X,
    const float* __restrict__ sc, const float* __restrict__ sh,
    const int* __restrict__ rowstart,
    const int* __restrict__ esrc, const float* __restrict__ epsArr, int layer,
    unsigned short* __restrict__ AGG)
{
    int wid = threadIdx.x >> 6, lane = threadIdx.x & 63;
    int row = blockIdx.x * 4 + wid;
    int half = lane >> 5;
    int c0 = (lane & 31) * 8;

    float s8[8], h8[8];
    if (AFF) {
        f32x4 a = *(const f32x4*)(sc + c0), b = *(const f32x4*)(sc + c0 + 4);
        f32x4 c = *(const f32x4*)(sh + c0), d = *(const f32x4*)(sh + c0 + 4);
        #pragma unroll
        for (int e = 0; e < 4; e++) { s8[e] = a[e]; s8[e + 4] = b[e]; h8[e] = c[e]; h8[e + 4] = d[e]; }
    }

    float a0[8] = {0,0,0,0,0,0,0,0}, a1[8] = {0,0,0,0,0,0,0,0};
    auto addv = [&](s16x8 u, float* a) {
        #pragma unroll
        for (int e = 0; e < 8; e++) {
            float f = bf2f((unsigned short)u[e]);
            if (AFF) f = fmaxf(f * s8[e] + h8[e], 0.f);
            a[e] += f;
        }
    };

    int s = rowstart[row], eEnd = rowstart[row + 1];
    int cnt = eEnd - s, mid = s + (cnt >> 1);
    int i = half ? mid : s;
    int end = half ? eEnd : mid;
    for (; i + 3 < end; i += 4) {
        int e0 = esrc[i], e1 = esrc[i + 1], e2 = esrc[i + 2], e3 = esrc[i + 3];
        s16x8 u0 = *(const s16x8*)(X + (size_t)e0 * H + c0);
        s16x8 u1 = *(const s16x8*)(X + (size_t)e1 * H + c0);
        s16x8 u2 = *(const s16x8*)(X + (size_t)e2 * H + c0);
        s16x8 u3 = *(const s16x8*)(X + (size_t)e3 * H + c0);
        addv(u0, a0); addv(u1, a1); addv(u2, a0); addv(u3, a1);
    }
    for (; i < end; ++i) {
        int e0 = esrc[i];
        s16x8 u = *(const s16x8*)(X + (size_t)e0 * H + c0);
        addv(u, a0);
    }

    if (half == 0) {   // self term
        float e1 = 1.0f + epsArr[layer];
        s16x8 u = *(const s16x8*)(X + (size_t)row * H + c0);
        #pragma unroll
        for (int e = 0; e < 8; e++) {
            float f = bf2f((unsigned short)u[e]);
            if (AFF) f = fmaxf(f * s8[e] + h8[e], 0.f);
            a0[e] += f * e1;
        }
    }

    s16x8 o;
    #pragma unroll
    for (int e = 0; e < 8; e++) {
        float tot = a0[e] + a1[e];
        tot += __shfl_xor(tot, 32);
        o[e] = (short)f2bf(tot);
    }
    if (half == 0)
        *(s16x8*)(AGG + (size_t)row * H + c0) = o;
}

// ---------------- weight prep ----------------
__global__ void prep_all_k(const float* __restrict__ Win, const float* __restrict__ w1,
                           const float* __restrict__ w2, unsigned short* __restrict__ BTall) {
    int i = blockIdx.x * 256 + threadIdx.x;
    const int NIN = 256 * KIN;
    if (i < NIN) {
        int n = i / KIN, k = i % KIN;
        BTall[i] = (k < FDIM) ? f2bf(Win[(size_t)k * 256 + n]) : (unsigned short)0;
    } else if (i < NIN + 6 * 65536) {
        int j = i - NIN;
        int d = j >> 16, r = j & 65535;
        int n = r >> 8, k = r & 255;
        const float* W = (d & 1) ? w2 : w1;
        BTall[i] = f2bf(W[(size_t)(d >> 1) * 65536 + (size_t)k * 256 + n]);
    }
}

// ---------------- segment mean ----------------
__global__ void molstart_k(const int* __restrict__ seg, int* __restrict__ ms) {
    int m = blockIdx.x * 256 + threadIdx.x;
    if (m <= NMOL) {
        int lo = 0, hi = NA;
        while (lo < hi) { int mid = (lo + hi) >> 1; if (seg[mid] < m) lo = mid + 1; else hi = mid; }
        ms[m] = lo;
    }
}
__global__ __launch_bounds__(64) void mean_k(const unsigned short* __restrict__ X,
    const float* __restrict__ sc, const float* __restrict__ sh,
    const int* __restrict__ ms, float* __restrict__ out)
{
    int m = blockIdx.x, lane = threadIdx.x;
    int half = lane >> 5;
    int c0 = (lane & 31) * 8;
    float s8[8], h8[8];
    {
        f32x4 a = *(const f32x4*)(sc + c0), b = *(const f32x4*)(sc + c0 + 4);
        f32x4 c = *(const f32x4*)(sh + c0), d = *(const f32x4*)(sh + c0 + 4);
        #pragma unroll
        for (int e = 0; e < 4; e++) { s8[e] = a[e]; s8[e + 4] = b[e]; h8[e] = c[e]; h8[e + 4] = d[e]; }
    }
    int a = ms[m], b = ms[m + 1];
    float acc[8] = {0,0,0,0,0,0,0,0};
    for (int r = a + half; r < b; r += 2) {
        s16x8 u = *(const s16x8*)(X + (size_t)r * H + c0);
        #pragma unroll
        for (int e = 0; e < 8; e++)
            acc[e] += fmaxf(bf2f((unsigned short)u[e]) * s8[e] + h8[e], 0.f);
    }
    float inv = (b > a) ? 1.0f / (float)(b - a) : 0.0f;
    f32x4 o0, o1;
    #pragma unroll
    for (int e = 0; e < 8; e++) {
        float tot = acc[e] + __shfl_xor(acc[e], 32);
        tot *= inv;
        if (e < 4) o0[e] = tot; else o1[e - 4] = tot;
    }
    if (half == 0) {
        *(f32x4*)(out + (size_t)m * H + c0) = o0;
        *(f32x4*)(out + (size_t)m * H + c0 + 4) = o1;
    }
}

extern "C" void kernel_launch(void* const* d_in, const int* in_sizes, int n_in,
                              void* d_out, int out_size, void* d_ws, size_t ws_size,
                              hipStream_t stream) {
    const float* f_atoms = (const float*)d_in[0];
    const float* W_in_w  = (const float*)d_in[1];
    const float* W_in_b  = (const float*)d_in[2];
    const float* w1  = (const float*)d_in[3];
    const float* b1  = (const float*)d_in[4];
    const float* g1  = (const float*)d_in[5];
    const float* be1 = (const float*)d_in[6];
    const float* w2  = (const float*)d_in[7];
    const float* b2  = (const float*)d_in[8];
    const float* g2  = (const float*)d_in[9];
    const float* be2 = (const float*)d_in[10];
    const float* epsArr = (const float*)d_in[11];
    const int* edge = (const int*)d_in[12];
    const int* seg  = (const int*)d_in[13];
    float* out = (float*)d_out;

    char* w = (char*)d_ws;
    size_t off = 0;
    auto alloc = [&](size_t bytes) {
        char* p = w + off;
        off = (off + bytes + 255) & ~(size_t)255;
        return p;
    };
    unsigned short* X   = (unsigned short*)alloc((size_t)NA * H * 2);
    unsigned short* AGG = (unsigned short*)alloc((size_t)NA * H * 2);
    unsigned short* T1  = (unsigned short*)alloc((size_t)NA * H * 2);
    unsigned short* BTall = (unsigned short*)alloc(((size_t)256 * KIN + 6 * 65536) * 2);
    float* stSum = (float*)alloc(256 * 4);
    float* stSq  = (float*)alloc(256 * 4);   // contiguous with stSum
    float* sc1 = (float*)alloc(256 * 4);
    float* sh1 = (float*)alloc(256 * 4);
    float* sc2 = (float*)alloc(256 * 4);
    float* sh2 = (float*)alloc(256 * 4);
    int* counts   = (int*)alloc((size_t)NA * 4);
    int* rowstart = (int*)alloc((size_t)(NA + 1) * 4);
    int* cursor   = (int*)alloc((size_t)NA * 4);
    int* esrc     = (int*)alloc((size_t)NE * 4);
    int* bsum     = (int*)alloc(512 * 4);
    int* ms       = (int*)alloc((NMOL + 1) * 4);
    int* ticket   = (int*)alloc(256);

    unsigned short* BTin = BTall;
    unsigned short* BT1[3], *BT2[3];
    for (int d = 0; d < 3; ++d) {
        BT1[d] = BTall + 256 * KIN + (size_t)(2 * d) * 65536;
        BT2[d] = BTall + 256 * KIN + (size_t)(2 * d + 1) * 65536;
    }

    const int* esrcIn = edge;        // edge_index[0] = src
    const int* edst   = edge + NE;   // edge_index[1] = dst

    zero_k<<<(NA + 255) / 256, 256, 0, stream>>>(counts, stSum, ticket, rowstart);
    prep_all_k<<<(256 * KIN + 6 * 65536 + 255) / 256, 256, 0, stream>>>(W_in_w, w1, w2, BTall);

    hist_k<<<(NE + 255) / 256, 256, 0, stream>>>(edst, counts);
    scan1_k<<<391, 256, 0, stream>>>(counts, rowstart, bsum);
    scan2_k<<<1, 512, 0, stream>>>(bsum, 391);
    scan3_k<<<391, 256, 0, stream>>>(rowstart, bsum, cursor);
    fill_k<<<(NE + 255) / 256, 256, 0, stream>>>(esrcIn, edst, cursor, esrc);
    molstart_k<<<(NMOL + 256) / 256, 256, 0, stream>>>(seg, ms);

    // x = relu(f_atoms @ W_in + b_in)
    gemmI_k<<<dim3(2, (NA + 127) / 128), 256, 0, stream>>>(f_atoms, BTin, W_in_b, X, NA);

    for (int d = 0; d < 3; ++d) {
        if (d == 0)
            agg_k<false><<<NA / 4, 256, 0, stream>>>(X, nullptr, nullptr,
                rowstart, esrc, epsArr, d, AGG);
        else
            agg_k<true><<<NA / 4, 256, 0, stream>>>(X, sc2, sh2,
                rowstart, esrc, epsArr, d, AGG);
        // T1 = AGG @ w1 + b1 (+stats+BN finalize -> sc1,sh1)
        gemmH_k<false><<<dim3(2, (NA + 127) / 128), 256, 0, stream>>>(
            AGG, BT1[d], b1 + d * 256, nullptr, nullptr, T1,
            stSum, stSq, ticket, g1 + d * 256, be1 + d * 256, sc1, sh1, NA);
        // X = relu(BN(T1)) @ w2 + b2 (+stats+BN finalize -> sc2,sh2)
        gemmH_k<true><<<dim3(2, (NA + 127) / 128), 256, 0, stream>>>(
            T1, BT2[d], b2 + d * 256, sc1, sh1, X,
            stSum, stSq, ticket, g2 + d * 256, be2 + d * 256, sc2, sh2, NA);
    }

    mean_k<<<NMOL, 64, 0, stream>>>(X, sc2, sh2, ms, out);
}

// Round 4
// 1618.977 us; speedup vs baseline: 1.0607x; 1.0607x over previous
//
#include <hip/hip_runtime.h>
#include <hip/hip_bf16.h>

#define NA 100000
#define NE 800000
#define FDIM 133
#define KIN 192          // 133 padded to 3*64
#define H 256
#define NMOL 4096

typedef __attribute__((ext_vector_type(8))) short s16x8;
typedef __attribute__((ext_vector_type(4))) float f32x4;

__device__ __forceinline__ float bf2f(unsigned short h) {
    unsigned u = ((unsigned)h) << 16;
    return __builtin_bit_cast(float, u);
}
__device__ __forceinline__ unsigned short f2bf(float f) {
    unsigned u = __builtin_bit_cast(unsigned, f);
    u = u + 0x7FFFu + ((u >> 16) & 1u);
    return (unsigned short)(u >> 16);
}

// element offset (in shorts) of 16B group g (0..7) of row (0..127) in a [128][64] bf16 tile,
// XOR-swizzled: staging places global group g at slot g^(row&7); read at swz(row,g) recovers it.
__device__ __forceinline__ int swz(int row, int g) {
    return row * 64 + ((g ^ (row & 7)) << 3);
}

__device__ __forceinline__ void gload_lds16(const void* g, void* l) {
    __builtin_amdgcn_global_load_lds((const __attribute__((address_space(1))) unsigned int*)g,
                                     (__attribute__((address_space(3))) unsigned int*)l, 16, 0, 0);
}

// ============ hidden GEMM: C[M][256] = A'[M][256] * BT[256][256]^T + bias, fused BN stats ============
// AFFINE: A' = relu(A*sc+sh) applied at A-frag build (BN+ReLU fold)
// column stats of fp32 output -> global atomics -> last-block(ticket) finalize writes scOut/shOut
template<bool AFFINE>
__global__ __launch_bounds__(256) void gemmH_k(
    const unsigned short* __restrict__ A,
    const unsigned short* __restrict__ BT,
    const float* __restrict__ bias,
    const float* __restrict__ aSc, const float* __restrict__ aSh,
    unsigned short* __restrict__ C,
    float* __restrict__ stSum, float* __restrict__ stSq, int* __restrict__ ticket,
    const float* __restrict__ g, const float* __restrict__ be,
    float* __restrict__ scOut, float* __restrict__ shOut,
    int M)
{
    __shared__ short lsA0[128 * 64], lsA1[128 * 64];
    __shared__ short lsB0[128 * 64], lsB1[128 * 64];
    __shared__ float lsSc[256], lsSh[256];
    __shared__ float lsS[128], lsQ[128];
    __shared__ int lsLast;

    const int t = threadIdx.x;
    const int m0 = blockIdx.y * 128;
    const int n0 = blockIdx.x * 128;

    if (t < 128) { lsS[t] = 0.f; lsQ[t] = 0.f; }
    if (AFFINE) { lsSc[t] = aSc[t]; lsSh[t] = aSh[t]; }

    const int lane = t & 63;
    const int wid = t >> 6;
    const int wm = wid >> 1, wn = wid & 1;
    const int fr = lane & 15, fg = lane >> 4;

    // direct-to-LDS staging: WAVE-UNIFORM LDS base (HW writes base + lane*16),
    // per-lane inverse-swizzled global source (both-sides-or-neither rule)
    auto stage = [&](int kc, short* dA, short* dB) {
        #pragma unroll
        for (int c = 0; c < 4; ++c) {
            int sb = __builtin_amdgcn_readfirstlane(c * 256 + wid * 64); // uniform 16B-slot base
            int slot = sb + lane;
            int row = slot >> 3, gs = slot & 7;
            int coff = kc * 64 + ((gs ^ (row & 7)) << 3);
            int rowA = m0 + row; if (rowA > M - 1) rowA = M - 1;   // branchless tail clamp
            gload_lds16(A + (size_t)rowA * 256 + coff, dA + (size_t)sb * 8);
            gload_lds16(BT + (size_t)(n0 + row) * 256 + coff, dB + (size_t)sb * 8);
        }
    };

    f32x4 acc[4][4];
    #pragma unroll
    for (int i = 0; i < 4; i++)
        #pragma unroll
        for (int j = 0; j < 4; j++)
            acc[i][j] = f32x4{0.f, 0.f, 0.f, 0.f};

    auto compute = [&](const short* bA, const short* bB, int kc) {
        #pragma unroll
        for (int ks = 0; ks < 2; ++ks) {
            s16x8 af[4], bg[4];
            #pragma unroll
            for (int mi = 0; mi < 4; ++mi)
                af[mi] = *(const s16x8*)&bA[swz(wm * 64 + mi * 16 + fr, ks * 4 + fg)];
            #pragma unroll
            for (int ni = 0; ni < 4; ++ni)
                bg[ni] = *(const s16x8*)&bB[swz(wn * 64 + ni * 16 + fr, ks * 4 + fg)];
            if (AFFINE) {
                int kb = kc * 64 + ks * 32 + fg * 8;
                f32x4 sA = *(const f32x4*)&lsSc[kb], sB = *(const f32x4*)&lsSc[kb + 4];
                f32x4 hA = *(const f32x4*)&lsSh[kb], hB = *(const f32x4*)&lsSh[kb + 4];
                #pragma unroll
                for (int mi = 0; mi < 4; ++mi) {
                    s16x8 v = af[mi];
                    #pragma unroll
                    for (int e = 0; e < 4; ++e) {
                        float f0 = fmaxf(bf2f((unsigned short)v[e]) * sA[e] + hA[e], 0.f);
                        float f1 = fmaxf(bf2f((unsigned short)v[e + 4]) * sB[e] + hB[e], 0.f);
                        v[e] = (short)f2bf(f0);
                        v[e + 4] = (short)f2bf(f1);
                    }
                    af[mi] = v;
                }
            }
            #pragma unroll
            for (int mi = 0; mi < 4; ++mi)
                #pragma unroll
                for (int ni = 0; ni < 4; ++ni)
                    acc[mi][ni] = __builtin_amdgcn_mfma_f32_16x16x32_bf16(
                        af[mi], bg[ni], acc[mi][ni], 0, 0, 0);
        }
    };

    stage(0, lsA0, lsB0);
    __syncthreads();                 // barrier drains vmcnt -> buf0 ready
    stage(1, lsA1, lsB1);            // prefetch in flight across chunk-0 MFMAs
    compute(lsA0, lsB0, 0);
    __syncthreads();
    stage(2, lsA0, lsB0);
    compute(lsA1, lsB1, 1);
    __syncthreads();
    stage(3, lsA1, lsB1);
    compute(lsA0, lsB0, 2);
    __syncthreads();
    compute(lsA1, lsB1, 3);

    // epilogue: C/D layout col=lane&15, row=(lane>>4)*4+reg
    #pragma unroll
    for (int ni = 0; ni < 4; ++ni) {
        int lcol = wn * 64 + ni * 16 + fr;
        float bc = bias[n0 + lcol];
        float cs = 0.f, cq = 0.f;
        #pragma unroll
        for (int mi = 0; mi < 4; ++mi) {
            #pragma unroll
            for (int r = 0; r < 4; ++r) {
                int row = m0 + wm * 64 + mi * 16 + fg * 4 + r;
                if (row < M) {
                    float v = acc[mi][ni][r] + bc;
                    cs += v; cq += v * v;
                    C[(size_t)row * H + n0 + lcol] = f2bf(v);
                }
            }
        }
        atomicAdd(&lsS[lcol], cs);
        atomicAdd(&lsQ[lcol], cq);
    }
    __syncthreads();
    if (t < 128) {
        atomicAdd(&stSum[n0 + t], lsS[t]);
        atomicAdd(&stSq[n0 + t], lsQ[t]);
    }
    __threadfence();
    __syncthreads();
    if (t == 0)
        lsLast = (atomicAdd(ticket, 1) == (int)(gridDim.x * gridDim.y) - 1) ? 1 : 0;
    __syncthreads();
    if (lsLast) {
        __threadfence();
        if (t < 256) {
            float mean = stSum[t] * (1.0f / (float)M);
            float var = stSq[t] * (1.0f / (float)M) - mean * mean;
            float sc = g[t] * rsqrtf(var + 1e-5f);
            scOut[t] = sc;
            shOut[t] = be[t] - mean * sc;
            stSum[t] = 0.f; stSq[t] = 0.f;   // ready for next stats pass
        }
        if (t == 0) *ticket = 0;
    }
}

// ============ input GEMM: X = relu(f_atoms[M][133] @ Win + b), reg-staged (f32->bf16 convert) ============
__global__ __launch_bounds__(256) void gemmI_k(
    const float* __restrict__ Af,
    const unsigned short* __restrict__ BT,
    const float* __restrict__ bias,
    unsigned short* __restrict__ C, int M)
{
    __shared__ short lsA[128 * 64];
    __shared__ short lsB[128 * 64];

    const int t = threadIdx.x;
    const int m0 = blockIdx.y * 128;
    const int n0 = blockIdx.x * 128;
    const int sr = t >> 3, sg = t & 7;
    const int lane = t & 63, wid = t >> 6;
    const int wm = wid >> 1, wn = wid & 1;
    const int fr = lane & 15, fg = lane >> 4;

    f32x4 acc[4][4];
    #pragma unroll
    for (int i = 0; i < 4; i++)
        #pragma unroll
        for (int j = 0; j < 4; j++)
            acc[i][j] = f32x4{0.f, 0.f, 0.f, 0.f};

    s16x8 ra[4], rb[4];
    auto loadRegs = [&](int kc) {
        const int k0 = kc * 64;
        #pragma unroll
        for (int p = 0; p < 4; ++p) {
            int r = p * 32 + sr;
            int ga = m0 + r;
            s16x8 v;
            #pragma unroll
            for (int e = 0; e < 8; ++e) {
                int k = k0 + sg * 8 + e;
                float f = (ga < M && k < FDIM) ? Af[(size_t)ga * FDIM + k] : 0.f;
                v[e] = (short)f2bf(f);
            }
            ra[p] = v;
            rb[p] = *(const s16x8*)(BT + (size_t)(n0 + r) * KIN + k0 + sg * 8);
        }
    };
    auto writeLds = [&]() {
        #pragma unroll
        for (int p = 0; p < 4; ++p) {
            int r = p * 32 + sr;
            *(s16x8*)&lsA[swz(r, sg)] = ra[p];
            *(s16x8*)&lsB[swz(r, sg)] = rb[p];
        }
    };

    loadRegs(0);
    for (int kc = 0; kc < 3; ++kc) {
        writeLds();
        __syncthreads();
        if (kc + 1 < 3) loadRegs(kc + 1);
        #pragma unroll
        for (int ks = 0; ks < 2; ++ks) {
            s16x8 af[4], bg[4];
            #pragma unroll
            for (int mi = 0; mi < 4; ++mi)
                af[mi] = *(const s16x8*)&lsA[swz(wm * 64 + mi * 16 + fr, ks * 4 + fg)];
            #pragma unroll
            for (int ni = 0; ni < 4; ++ni)
                bg[ni] = *(const s16x8*)&lsB[swz(wn * 64 + ni * 16 + fr, ks * 4 + fg)];
            #pragma unroll
            for (int mi = 0; mi < 4; ++mi)
                #pragma unroll
                for (int ni = 0; ni < 4; ++ni)
                    acc[mi][ni] = __builtin_amdgcn_mfma_f32_16x16x32_bf16(
                        af[mi], bg[ni], acc[mi][ni], 0, 0, 0);
        }
        __syncthreads();
    }

    #pragma unroll
    for (int ni = 0; ni < 4; ++ni) {
        float bc = bias[n0 + wn * 64 + ni * 16 + fr];
        #pragma unroll
        for (int mi = 0; mi < 4; ++mi) {
            #pragma unroll
            for (int r = 0; r < 4; ++r) {
                int row = m0 + wm * 64 + mi * 16 + fg * 4 + r;
                if (row < M) {
                    float v = fmaxf(acc[mi][ni][r] + bc, 0.f);
                    C[(size_t)row * H + n0 + wn * 64 + ni * 16 + fr] = f2bf(v);
                }
            }
        }
    }
}

// ---------------- init ----------------
__global__ void zero_k(int* __restrict__ counts, float* __restrict__ st,
                       int* __restrict__ ticket, int* __restrict__ rowstart) {
    int i = blockIdx.x * 256 + threadIdx.x;
    if (i < NA) counts[i] = 0;
    if (blockIdx.x == 0) {
        st[threadIdx.x] = 0.f; st[threadIdx.x + 256] = 0.f;
        if (threadIdx.x == 0) { *ticket = 0; rowstart[NA] = NE; }
    }
}

// ---------------- CSR build ----------------
__global__ void hist_k(const int* __restrict__ dst, int* __restrict__ counts) {
    int e = blockIdx.x * 256 + threadIdx.x;
    if (e < NE) atomicAdd(&counts[dst[e]], 1);
}
__global__ void scan1_k(const int* __restrict__ counts, int* __restrict__ excl, int* __restrict__ bsum) {
    __shared__ int sd[256];
    int i = blockIdx.x * 256 + threadIdx.x;
    int c = (i < NA) ? counts[i] : 0;
    sd[threadIdx.x] = c;
    __syncthreads();
    for (int off = 1; off < 256; off <<= 1) {
        int v = (threadIdx.x >= off) ? sd[threadIdx.x - off] : 0;
        __syncthreads();
        sd[threadIdx.x] += v;
        __syncthreads();
    }
    if (i < NA) excl[i] = sd[threadIdx.x] - c;
    if (threadIdx.x == 255) bsum[blockIdx.x] = sd[255];
}
__global__ void scan2_k(int* __restrict__ bsum, int nb) {
    __shared__ int sd[512];
    int t = threadIdx.x;
    int v = (t < nb) ? bsum[t] : 0;
    sd[t] = v;
    __syncthreads();
    for (int off = 1; off < 512; off <<= 1) {
        int u = (t >= off) ? sd[t - off] : 0;
        __syncthreads();
        sd[t] += u;
        __syncthreads();
    }
    if (t < nb) bsum[t] = sd[t] - v;
}
__global__ void scan3_k(int* __restrict__ rowstart, const int* __restrict__ bsum, int* __restrict__ cursor) {
    int i = blockIdx.x * 256 + threadIdx.x;
    if (i < NA) {
        int v = rowstart[i] + bsum[blockIdx.x];
        rowstart[i] = v;
        cursor[i] = v;
    }
}
__global__ void fill_k(const int* __restrict__ src, const int* __restrict__ dstArr,
                       int* __restrict__ cursor, int* __restrict__ esrc) {
    int e = blockIdx.x * 256 + threadIdx.x;
    if (e < NE) {
        int d = dstArr[e];
        int pos = atomicAdd(&cursor[d], 1);
        esrc[pos] = src[e];
    }
}

// ---------------- neighbor aggregation ----------------
// one row/wave; halves walk contiguous sub-ranges, 4 gathers in flight; shfl merge
template<bool AFF>
__global__ __launch_bounds__(256) void agg_k(const unsigned short* __restrict__ X,
    const float* __restrict__ sc, const float* __restrict__ sh,
    const int* __restrict__ rowstart,
    const int* __restrict__ esrc, const float* __restrict__ epsArr, int layer,
    unsigned short* __restrict__ AGG)
{
    int wid = threadIdx.x >> 6, lane = threadIdx.x & 63;
    int row = blockIdx.x * 4 + wid;
    int half = lane >> 5;
    int c0 = (lane & 31) * 8;

    float s8[8], h8[8];
    if (AFF) {
        f32x4 a = *(const f32x4*)(sc + c0), b = *(const f32x4*)(sc + c0 + 4);
        f32x4 c = *(const f32x4*)(sh + c0), d = *(const f32x4*)(sh + c0 + 4);
        #pragma unroll
        for (int e = 0; e < 4; e++) { s8[e] = a[e]; s8[e + 4] = b[e]; h8[e] = c[e]; h8[e + 4] = d[e]; }
    }

    float a0[8] = {0,0,0,0,0,0,0,0}, a1[8] = {0,0,0,0,0,0,0,0};
    auto addv = [&](s16x8 u, float* a) {
        #pragma unroll
        for (int e = 0; e < 8; e++) {
            float f = bf2f((unsigned short)u[e]);
            if (AFF) f = fmaxf(f * s8[e] + h8[e], 0.f);
            a[e] += f;
        }
    };

    int s = rowstart[row], eEnd = rowstart[row + 1];
    int cnt = eEnd - s, mid = s + (cnt >> 1);
    int i = half ? mid : s;
    int end = half ? eEnd : mid;
    for (; i + 3 < end; i += 4) {
        int e0 = esrc[i], e1 = esrc[i + 1], e2 = esrc[i + 2], e3 = esrc[i + 3];
        s16x8 u0 = *(const s16x8*)(X + (size_t)e0 * H + c0);
        s16x8 u1 = *(const s16x8*)(X + (size_t)e1 * H + c0);
        s16x8 u2 = *(const s16x8*)(X + (size_t)e2 * H + c0);
        s16x8 u3 = *(const s16x8*)(X + (size_t)e3 * H + c0);
        addv(u0, a0); addv(u1, a1); addv(u2, a0); addv(u3, a1);
    }
    for (; i < end; ++i) {
        int e0 = esrc[i];
        s16x8 u = *(const s16x8*)(X + (size_t)e0 * H + c0);
        addv(u, a0);
    }

    if (half == 0) {   // self term
        float e1 = 1.0f + epsArr[layer];
        s16x8 u = *(const s16x8*)(X + (size_t)row * H + c0);
        #pragma unroll
        for (int e = 0; e < 8; e++) {
            float f = bf2f((unsigned short)u[e]);
            if (AFF) f = fmaxf(f * s8[e] + h8[e], 0.f);
            a0[e] += f * e1;
        }
    }

    s16x8 o;
    #pragma unroll
    for (int e = 0; e < 8; e++) {
        float tot = a0[e] + a1[e];
        tot += __shfl_xor(tot, 32);
        o[e] = (short)f2bf(tot);
    }
    if (half == 0)
        *(s16x8*)(AGG + (size_t)row * H + c0) = o;
}

// ---------------- weight prep ----------------
__global__ void prep_all_k(const float* __restrict__ Win, const float* __restrict__ w1,
                           const float* __restrict__ w2, unsigned short* __restrict__ BTall) {
    int i = blockIdx.x * 256 + threadIdx.x;
    const int NIN = 256 * KIN;
    if (i < NIN) {
        int n = i / KIN, k = i % KIN;
        BTall[i] = (k < FDIM) ? f2bf(Win[(size_t)k * 256 + n]) : (unsigned short)0;
    } else if (i < NIN + 6 * 65536) {
        int j = i - NIN;
        int d = j >> 16, r = j & 65535;
        int n = r >> 8, k = r & 255;
        const float* W = (d & 1) ? w2 : w1;
        BTall[i] = f2bf(W[(size_t)(d >> 1) * 65536 + (size_t)k * 256 + n]);
    }
}

// ---------------- segment mean ----------------
__global__ void molstart_k(const int* __restrict__ seg, int* __restrict__ ms) {
    int m = blockIdx.x * 256 + threadIdx.x;
    if (m <= NMOL) {
        int lo = 0, hi = NA;
        while (lo < hi) { int mid = (lo + hi) >> 1; if (seg[mid] < m) lo = mid + 1; else hi = mid; }
        ms[m] = lo;
    }
}
__global__ __launch_bounds__(64) void mean_k(const unsigned short* __restrict__ X,
    const float* __restrict__ sc, const float* __restrict__ sh,
    const int* __restrict__ ms, float* __restrict__ out)
{
    int m = blockIdx.x, lane = threadIdx.x;
    int half = lane >> 5;
    int c0 = (lane & 31) * 8;
    float s8[8], h8[8];
    {
        f32x4 a = *(const f32x4*)(sc + c0), b = *(const f32x4*)(sc + c0 + 4);
        f32x4 c = *(const f32x4*)(sh + c0), d = *(const f32x4*)(sh + c0 + 4);
        #pragma unroll
        for (int e = 0; e < 4; e++) { s8[e] = a[e]; s8[e + 4] = b[e]; h8[e] = c[e]; h8[e + 4] = d[e]; }
    }
    int a = ms[m], b = ms[m + 1];
    float acc[8] = {0,0,0,0,0,0,0,0};
    for (int r = a + half; r < b; r += 2) {
        s16x8 u = *(const s16x8*)(X + (size_t)r * H + c0);
        #pragma unroll
        for (int e = 0; e < 8; e++)
            acc[e] += fmaxf(bf2f((unsigned short)u[e]) * s8[e] + h8[e], 0.f);
    }
    float inv = (b > a) ? 1.0f / (float)(b - a) : 0.0f;
    f32x4 o0, o1;
    #pragma unroll
    for (int e = 0; e < 8; e++) {
        float tot = acc[e] + __shfl_xor(acc[e], 32);
        tot *= inv;
        if (e < 4) o0[e] = tot; else o1[e - 4] = tot;
    }
    if (half == 0) {
        *(f32x4*)(out + (size_t)m * H + c0) = o0;
        *(f32x4*)(out + (size_t)m * H + c0 + 4) = o1;
    }
}

extern "C" void kernel_launch(void* const* d_in, const int* in_sizes, int n_in,
                              void* d_out, int out_size, void* d_ws, size_t ws_size,
                              hipStream_t stream) {
    const float* f_atoms = (const float*)d_in[0];
    const float* W_in_w  = (const float*)d_in[1];
    const float* W_in_b  = (const float*)d_in[2];
    const float* w1  = (const float*)d_in[3];
    const float* b1  = (const float*)d_in[4];
    const float* g1  = (const float*)d_in[5];
    const float* be1 = (const float*)d_in[6];
    const float* w2  = (const float*)d_in[7];
    const float* b2  = (const float*)d_in[8];
    const float* g2  = (const float*)d_in[9];
    const float* be2 = (const float*)d_in[10];
    const float* epsArr = (const float*)d_in[11];
    const int* edge = (const int*)d_in[12];
    const int* seg  = (const int*)d_in[13];
    float* out = (float*)d_out;

    char* w = (char*)d_ws;
    size_t off = 0;
    auto alloc = [&](size_t bytes) {
        char* p = w + off;
        off = (off + bytes + 255) & ~(size_t)255;
        return p;
    };
    unsigned short* X   = (unsigned short*)alloc((size_t)NA * H * 2);
    unsigned short* AGG = (unsigned short*)alloc((size_t)NA * H * 2);
    unsigned short* T1  = (unsigned short*)alloc((size_t)NA * H * 2);
    unsigned short* BTall = (unsigned short*)alloc(((size_t)256 * KIN + 6 * 65536) * 2);
    float* stSum = (float*)alloc(256 * 4);
    float* stSq  = (float*)alloc(256 * 4);   // contiguous with stSum
    float* sc1 = (float*)alloc(256 * 4);
    float* sh1 = (float*)alloc(256 * 4);
    float* sc2 = (float*)alloc(256 * 4);
    float* sh2 = (float*)alloc(256 * 4);
    int* counts   = (int*)alloc((size_t)NA * 4);
    int* rowstart = (int*)alloc((size_t)(NA + 1) * 4);
    int* cursor   = (int*)alloc((size_t)NA * 4);
    int* esrc     = (int*)alloc((size_t)NE * 4);
    int* bsum     = (int*)alloc(512 * 4);
    int* ms       = (int*)alloc((NMOL + 1) * 4);
    int* ticket   = (int*)alloc(256);

    unsigned short* BTin = BTall;
    unsigned short* BT1[3], *BT2[3];
    for (int d = 0; d < 3; ++d) {
        BT1[d] = BTall + 256 * KIN + (size_t)(2 * d) * 65536;
        BT2[d] = BTall + 256 * KIN + (size_t)(2 * d + 1) * 65536;
    }

    const int* esrcIn = edge;        // edge_index[0] = src
    const int* edst   = edge + NE;   // edge_index[1] = dst

    zero_k<<<(NA + 255) / 256, 256, 0, stream>>>(counts, stSum, ticket, rowstart);
    prep_all_k<<<(256 * KIN + 6 * 65536 + 255) / 256, 256, 0, stream>>>(W_in_w, w1, w2, BTall);

    hist_k<<<(NE + 255) / 256, 256, 0, stream>>>(edst, counts);
    scan1_k<<<391, 256, 0, stream>>>(counts, rowstart, bsum);
    scan2_k<<<1, 512, 0, stream>>>(bsum, 391);
    scan3_k<<<391, 256, 0, stream>>>(rowstart, bsum, cursor);
    fill_k<<<(NE + 255) / 256, 256, 0, stream>>>(esrcIn, edst, cursor, esrc);
    molstart_k<<<(NMOL + 256) / 256, 256, 0, stream>>>(seg, ms);

    // x = relu(f_atoms @ W_in + b_in)
    gemmI_k<<<dim3(2, (NA + 127) / 128), 256, 0, stream>>>(f_atoms, BTin, W_in_b, X, NA);

    for (int d = 0; d < 3; ++d) {
        if (d == 0)
            agg_k<false><<<NA / 4, 256, 0, stream>>>(X, nullptr, nullptr,
                rowstart, esrc, epsArr, d, AGG);
        else
            agg_k<true><<<NA / 4, 256, 0, stream>>>(X, sc2, sh2,
                rowstart, esrc, epsArr, d, AGG);
        // T1 = AGG @ w1 + b1 (+stats+BN finalize -> sc1,sh1)
        gemmH_k<false><<<dim3(2, (NA + 127) / 128), 256, 0, stream>>>(
            AGG, BT1[d], b1 + d * 256, nullptr, nullptr, T1,
            stSum, stSq, ticket, g1 + d * 256, be1 + d * 256, sc1, sh1, NA);
        // X = relu(BN(T1)) @ w2 + b2 (+stats+BN finalize -> sc2,sh2)
        gemmH_k<true><<<dim3(2, (NA + 127) / 128), 256, 0, stream>>>(
            T1, BT2[d], b2 + d * 256, sc1, sh1, X,
            stSum, stSq, ticket, g2 + d * 256, be2 + d * 256, sc2, sh2, NA);
    }

    mean_k<<<NMOL, 64, 0, stream>>>(X, sc2, sh2, ms, out);
}

// Round 5
// 785.365 us; speedup vs baseline: 2.1865x; 2.0614x over previous
//
#include <hip/hip_runtime.h>
#include <hip/hip_bf16.h>

#define NA 100000
#define NE 800000
#define FDIM 133
#define KIN 192          // 133 padded to 3*64
#define H 256
#define NMOL 4096

typedef __attribute__((ext_vector_type(8))) short s16x8;
typedef __attribute__((ext_vector_type(4))) float f32x4;

__device__ __forceinline__ float bf2f(unsigned short h) {
    unsigned u = ((unsigned)h) << 16;
    return __builtin_bit_cast(float, u);
}
__device__ __forceinline__ unsigned short f2bf(float f) {
    unsigned u = __builtin_bit_cast(unsigned, f);
    u = u + 0x7FFFu + ((u >> 16) & 1u);
    return (unsigned short)(u >> 16);
}

// element offset (in shorts) of 16B group g (0..7) of row (0..127) in a [128][64] bf16 tile,
// XOR-swizzled so both ds_write_b128 staging and MFMA-frag ds_read_b128 are conflict-optimal
__device__ __forceinline__ int swz(int row, int g) {
    return row * 64 + ((g ^ (row & 7)) << 3);
}

// ---------------- GEMM: C[M][256] = A[M][Kpad] * BT[256][Kpad]^T (+bias) ----------------
// Round-2 proven structure: reg-staged, single-buffer LDS, 2 barriers/chunk.
// A_F32:    A is fp32 [M][FDIM] (zero-pad to Kpad during staging)
// AFFINE:   A' = relu(A*aSc[k]+aSh[k]) applied during staging (folds previous BN+ReLU)
// RELU_OUT: relu on output (input layer)
// STATS:    accumulate column sum/sumsq of fp32 output into stSum/stSq (LDS-reduced, 1 atomic/col/block)
template<bool A_F32, bool AFFINE, bool RELU_OUT, bool STATS>
__global__ __launch_bounds__(256) void gemm_k(
    const void* __restrict__ Avoid,
    const unsigned short* __restrict__ BT,
    const float* __restrict__ bias,
    const float* __restrict__ aSc, const float* __restrict__ aSh,
    unsigned short* __restrict__ C,
    float* __restrict__ stSum, float* __restrict__ stSq,
    int M, int Kpad)
{
    __shared__ short lsA[128 * 64];
    __shared__ short lsB[128 * 64];
    __shared__ float lsSc[256], lsSh[256];
    __shared__ float lsS[128], lsQ[128];

    const int t = threadIdx.x;
    const int m0 = blockIdx.y * 128;
    const int n0 = blockIdx.x * 128;

    if (STATS && t < 128) { lsS[t] = 0.f; lsQ[t] = 0.f; }
    if (AFFINE) { lsSc[t] = aSc[t]; lsSh[t] = aSh[t]; }
    if (AFFINE) __syncthreads();

    const int sr = t >> 3;          // staging row-in-pass 0..31
    const int sg = t & 7;           // staging 16B group 0..7
    const int lane = t & 63;
    const int wid = t >> 6;
    const int wm = wid >> 1, wn = wid & 1;
    const int fr = lane & 15, fg = lane >> 4;

    f32x4 acc[4][4];
    #pragma unroll
    for (int i = 0; i < 4; i++)
        #pragma unroll
        for (int j = 0; j < 4; j++)
            acc[i][j] = f32x4{0.f, 0.f, 0.f, 0.f};

    const int nK = Kpad >> 6;
    s16x8 ra[4], rb[4];

    auto loadRegs = [&](int kc) {
        const int k0 = kc * 64;
        #pragma unroll
        for (int p = 0; p < 4; ++p) {
            int r = p * 32 + sr;
            int ga = m0 + r;
            if (A_F32) {
                const float* Af = (const float*)Avoid;
                s16x8 v;
                #pragma unroll
                for (int e = 0; e < 8; ++e) {
                    int k = k0 + sg * 8 + e;
                    float f = (ga < M && k < FDIM) ? Af[(size_t)ga * FDIM + k] : 0.f;
                    v[e] = (short)f2bf(f);
                }
                ra[p] = v;
            } else {
                const unsigned short* A = (const unsigned short*)Avoid;
                s16x8 z = {0,0,0,0,0,0,0,0};
                ra[p] = (ga < M) ? *(const s16x8*)(A + (size_t)ga * Kpad + k0 + sg * 8) : z;
            }
            rb[p] = *(const s16x8*)(BT + (size_t)(n0 + r) * Kpad + k0 + sg * 8);
        }
    };
    auto writeLds = [&](int kc) {
        const int k0 = kc * 64;
        #pragma unroll
        for (int p = 0; p < 4; ++p) {
            int r = p * 32 + sr;
            s16x8 va = ra[p];
            if (AFFINE) {
                #pragma unroll
                for (int e = 0; e < 8; ++e) {
                    int k = k0 + sg * 8 + e;
                    float f = bf2f((unsigned short)va[e]);
                    f = fmaxf(f * lsSc[k] + lsSh[k], 0.f);
                    va[e] = (short)f2bf(f);
                }
            }
            *(s16x8*)&lsA[swz(r, sg)] = va;
            *(s16x8*)&lsB[swz(r, sg)] = rb[p];
        }
    };

    loadRegs(0);
    for (int kc = 0; kc < nK; ++kc) {
        writeLds(kc);
        __syncthreads();
        if (kc + 1 < nK) loadRegs(kc + 1);   // next-chunk loads in flight across MFMAs
        #pragma unroll
        for (int ks = 0; ks < 2; ++ks) {
            s16x8 af[4], bg[4];
            #pragma unroll
            for (int mi = 0; mi < 4; ++mi)
                af[mi] = *(const s16x8*)&lsA[swz(wm * 64 + mi * 16 + fr, ks * 4 + fg)];
            #pragma unroll
            for (int ni = 0; ni < 4; ++ni)
                bg[ni] = *(const s16x8*)&lsB[swz(wn * 64 + ni * 16 + fr, ks * 4 + fg)];
            #pragma unroll
            for (int mi = 0; mi < 4; ++mi)
                #pragma unroll
                for (int ni = 0; ni < 4; ++ni)
                    acc[mi][ni] = __builtin_amdgcn_mfma_f32_16x16x32_bf16(
                        af[mi], bg[ni], acc[mi][ni], 0, 0, 0);
        }
        __syncthreads();
    }

    // epilogue: C/D layout col = lane&15, row = (lane>>4)*4 + reg
    #pragma unroll
    for (int ni = 0; ni < 4; ++ni) {
        int lcol = wn * 64 + ni * 16 + fr;
        float bc = bias[n0 + lcol];
        float cs = 0.f, cq = 0.f;
        #pragma unroll
        for (int mi = 0; mi < 4; ++mi) {
            #pragma unroll
            for (int r = 0; r < 4; ++r) {
                int row = m0 + wm * 64 + mi * 16 + fg * 4 + r;
                if (row < M) {
                    float v = acc[mi][ni][r] + bc;
                    if (RELU_OUT) v = fmaxf(v, 0.f);
                    if (STATS) { cs += v; cq += v * v; }
                    C[(size_t)row * H + n0 + lcol] = f2bf(v);
                }
            }
        }
        if (STATS) {
            atomicAdd(&lsS[lcol], cs);
            atomicAdd(&lsQ[lcol], cq);
        }
    }
    if (STATS) {
        __syncthreads();
        if (t < 128) {
            atomicAdd(&stSum[n0 + t], lsS[t]);
            atomicAdd(&stSq[n0 + t], lsQ[t]);
        }
    }
}

__global__ void bnfin_k(float* __restrict__ sum, float* __restrict__ sumsq,
                        const float* __restrict__ g, const float* __restrict__ be,
                        float* __restrict__ scOut, float* __restrict__ shOut) {
    int c = threadIdx.x;
    float mean = sum[c] * (1.0f / NA);
    float var = sumsq[c] * (1.0f / NA) - mean * mean;
    float sc = g[c] * rsqrtf(var + 1e-5f);
    scOut[c] = sc;
    shOut[c] = be[c] - mean * sc;
    sum[c] = 0.f; sumsq[c] = 0.f;   // ready for next use
}

// ---------------- init ----------------
__global__ void zero_k(int* __restrict__ counts, float* __restrict__ st, int* __restrict__ rowstart) {
    int i = blockIdx.x * 256 + threadIdx.x;
    if (i < NA) counts[i] = 0;
    if (blockIdx.x == 0) {
        st[threadIdx.x] = 0.f; st[threadIdx.x + 256] = 0.f;
        if (threadIdx.x == 0) rowstart[NA] = NE;
    }
}

// ---------------- CSR build ----------------
__global__ void hist_k(const int* __restrict__ dst, int* __restrict__ counts) {
    int e = blockIdx.x * 256 + threadIdx.x;
    if (e < NE) atomicAdd(&counts[dst[e]], 1);
}
__global__ void scan1_k(const int* __restrict__ counts, int* __restrict__ excl, int* __restrict__ bsum) {
    __shared__ int sd[256];
    int i = blockIdx.x * 256 + threadIdx.x;
    int c = (i < NA) ? counts[i] : 0;
    sd[threadIdx.x] = c;
    __syncthreads();
    for (int off = 1; off < 256; off <<= 1) {
        int v = (threadIdx.x >= off) ? sd[threadIdx.x - off] : 0;
        __syncthreads();
        sd[threadIdx.x] += v;
        __syncthreads();
    }
    if (i < NA) excl[i] = sd[threadIdx.x] - c;
    if (threadIdx.x == 255) bsum[blockIdx.x] = sd[255];
}
__global__ void scan2_k(int* __restrict__ bsum, int nb) {
    __shared__ int sd[512];
    int t = threadIdx.x;
    int v = (t < nb) ? bsum[t] : 0;
    sd[t] = v;
    __syncthreads();
    for (int off = 1; off < 512; off <<= 1) {
        int u = (t >= off) ? sd[t - off] : 0;
        __syncthreads();
        sd[t] += u;
        __syncthreads();
    }
    if (t < nb) bsum[t] = sd[t] - v;
}
__global__ void scan3_k(int* __restrict__ rowstart, const int* __restrict__ bsum, int* __restrict__ cursor) {
    int i = blockIdx.x * 256 + threadIdx.x;
    if (i < NA) {
        int v = rowstart[i] + bsum[blockIdx.x];
        rowstart[i] = v;
        cursor[i] = v;
    }
}
__global__ void fill_k(const int* __restrict__ src, const int* __restrict__ dstArr,
                       int* __restrict__ cursor, int* __restrict__ esrc) {
    int e = blockIdx.x * 256 + threadIdx.x;
    if (e < NE) {
        int d = dstArr[e];
        int pos = atomicAdd(&cursor[d], 1);
        esrc[pos] = src[e];
    }
}

// ---------------- neighbor aggregation ----------------
// one row/wave; halves walk contiguous sub-ranges, 4 gathers in flight; shfl merge
template<bool AFF>
__global__ __launch_bounds__(256) void agg_k(const unsigned short* __restrict__ X,
    const float* __restrict__ sc, const float* __restrict__ sh,
    const int* __restrict__ rowstart,
    const int* __restrict__ esrc, const float* __restrict__ epsArr, int layer,
    unsigned short* __restrict__ AGG)
{
    int wid = threadIdx.x >> 6, lane = threadIdx.x & 63;
    int row = blockIdx.x * 4 + wid;
    int half = lane >> 5;
    int c0 = (lane & 31) * 8;

    float s8[8], h8[8];
    if (AFF) {
        f32x4 a = *(const f32x4*)(sc + c0), b = *(const f32x4*)(sc + c0 + 4);
        f32x4 c = *(const f32x4*)(sh + c0), d = *(const f32x4*)(sh + c0 + 4);
        #pragma unroll
        for (int e = 0; e < 4; e++) { s8[e] = a[e]; s8[e + 4] = b[e]; h8[e] = c[e]; h8[e + 4] = d[e]; }
    }

    float a0[8] = {0,0,0,0,0,0,0,0}, a1[8] = {0,0,0,0,0,0,0,0};
    auto addv = [&](s16x8 u, float* a) {
        #pragma unroll
        for (int e = 0; e < 8; e++) {
            float f = bf2f((unsigned short)u[e]);
            if (AFF) f = fmaxf(f * s8[e] + h8[e], 0.f);
            a[e] += f;
        }
    };

    int s = rowstart[row], eEnd = rowstart[row + 1];
    int cnt = eEnd - s, mid = s + (cnt >> 1);
    int i = half ? mid : s;
    int end = half ? eEnd : mid;
    for (; i + 3 < end; i += 4) {
        int e0 = esrc[i], e1 = esrc[i + 1], e2 = esrc[i + 2], e3 = esrc[i + 3];
        s16x8 u0 = *(const s16x8*)(X + (size_t)e0 * H + c0);
        s16x8 u1 = *(const s16x8*)(X + (size_t)e1 * H + c0);
        s16x8 u2 = *(const s16x8*)(X + (size_t)e2 * H + c0);
        s16x8 u3 = *(const s16x8*)(X + (size_t)e3 * H + c0);
        addv(u0, a0); addv(u1, a1); addv(u2, a0); addv(u3, a1);
    }
    for (; i < end; ++i) {
        int e0 = esrc[i];
        s16x8 u = *(const s16x8*)(X + (size_t)e0 * H + c0);
        addv(u, a0);
    }

    if (half == 0) {   // self term
        float e1 = 1.0f + epsArr[layer];
        s16x8 u = *(const s16x8*)(X + (size_t)row * H + c0);
        #pragma unroll
        for (int e = 0; e < 8; e++) {
            float f = bf2f((unsigned short)u[e]);
            if (AFF) f = fmaxf(f * s8[e] + h8[e], 0.f);
            a0[e] += f * e1;
        }
    }

    s16x8 o;
    #pragma unroll
    for (int e = 0; e < 8; e++) {
        float tot = a0[e] + a1[e];
        tot += __shfl_xor(tot, 32);
        o[e] = (short)f2bf(tot);
    }
    if (half == 0)
        *(s16x8*)(AGG + (size_t)row * H + c0) = o;
}

// ---------------- weight prep ----------------
__global__ void prep_all_k(const float* __restrict__ Win, const float* __restrict__ w1,
                           const float* __restrict__ w2, unsigned short* __restrict__ BTall) {
    int i = blockIdx.x * 256 + threadIdx.x;
    const int NIN = 256 * KIN;
    if (i < NIN) {
        int n = i / KIN, k = i % KIN;
        BTall[i] = (k < FDIM) ? f2bf(Win[(size_t)k * 256 + n]) : (unsigned short)0;
    } else if (i < NIN + 6 * 65536) {
        int j = i - NIN;
        int d = j >> 16, r = j & 65535;
        int n = r >> 8, k = r & 255;
        const float* W = (d & 1) ? w2 : w1;
        BTall[i] = f2bf(W[(size_t)(d >> 1) * 65536 + (size_t)k * 256 + n]);
    }
}

// ---------------- segment mean ----------------
__global__ void molstart_k(const int* __restrict__ seg, int* __restrict__ ms) {
    int m = blockIdx.x * 256 + threadIdx.x;
    if (m <= NMOL) {
        int lo = 0, hi = NA;
        while (lo < hi) { int mid = (lo + hi) >> 1; if (seg[mid] < m) lo = mid + 1; else hi = mid; }
        ms[m] = lo;
    }
}
__global__ __launch_bounds__(64) void mean_k(const unsigned short* __restrict__ X,
    const float* __restrict__ sc, const float* __restrict__ sh,
    const int* __restrict__ ms, float* __restrict__ out)
{
    int m = blockIdx.x, lane = threadIdx.x;
    int half = lane >> 5;
    int c0 = (lane & 31) * 8;
    float s8[8], h8[8];
    {
        f32x4 a = *(const f32x4*)(sc + c0), b = *(const f32x4*)(sc + c0 + 4);
        f32x4 c = *(const f32x4*)(sh + c0), d = *(const f32x4*)(sh + c0 + 4);
        #pragma unroll
        for (int e = 0; e < 4; e++) { s8[e] = a[e]; s8[e + 4] = b[e]; h8[e] = c[e]; h8[e + 4] = d[e]; }
    }
    int a = ms[m], b = ms[m + 1];
    float acc[8] = {0,0,0,0,0,0,0,0};
    for (int r = a + half; r < b; r += 2) {
        s16x8 u = *(const s16x8*)(X + (size_t)r * H + c0);
        #pragma unroll
        for (int e = 0; e < 8; e++)
            acc[e] += fmaxf(bf2f((unsigned short)u[e]) * s8[e] + h8[e], 0.f);
    }
    float inv = (b > a) ? 1.0f / (float)(b - a) : 0.0f;
    f32x4 o0, o1;
    #pragma unroll
    for (int e = 0; e < 8; e++) {
        float tot = acc[e] + __shfl_xor(acc[e], 32);
        tot *= inv;
        if (e < 4) o0[e] = tot; else o1[e - 4] = tot;
    }
    if (half == 0) {
        *(f32x4*)(out + (size_t)m * H + c0) = o0;
        *(f32x4*)(out + (size_t)m * H + c0 + 4) = o1;
    }
}

extern "C" void kernel_launch(void* const* d_in, const int* in_sizes, int n_in,
                              void* d_out, int out_size, void* d_ws, size_t ws_size,
                              hipStream_t stream) {
    const float* f_atoms = (const float*)d_in[0];
    const float* W_in_w  = (const float*)d_in[1];
    const float* W_in_b  = (const float*)d_in[2];
    const float* w1  = (const float*)d_in[3];
    const float* b1  = (const float*)d_in[4];
    const float* g1  = (const float*)d_in[5];
    const float* be1 = (const float*)d_in[6];
    const float* w2  = (const float*)d_in[7];
    const float* b2  = (const float*)d_in[8];
    const float* g2  = (const float*)d_in[9];
    const float* be2 = (const float*)d_in[10];
    const float* epsArr = (const float*)d_in[11];
    const int* edge = (const int*)d_in[12];
    const int* seg  = (const int*)d_in[13];
    float* out = (float*)d_out;

    char* w = (char*)d_ws;
    size_t off = 0;
    auto alloc = [&](size_t bytes) {
        char* p = w + off;
        off = (off + bytes + 255) & ~(size_t)255;
        return p;
    };
    unsigned short* X   = (unsigned short*)alloc((size_t)NA * H * 2);
    unsigned short* AGG = (unsigned short*)alloc((size_t)NA * H * 2);
    unsigned short* T1  = (unsigned short*)alloc((size_t)NA * H * 2);
    unsigned short* BTall = (unsigned short*)alloc(((size_t)256 * KIN + 6 * 65536) * 2);
    float* stSum = (float*)alloc(256 * 4);
    float* stSq  = (float*)alloc(256 * 4);   // contiguous with stSum
    float* sc1 = (float*)alloc(256 * 4);
    float* sh1 = (float*)alloc(256 * 4);
    float* sc2 = (float*)alloc(256 * 4);
    float* sh2 = (float*)alloc(256 * 4);
    int* counts   = (int*)alloc((size_t)NA * 4);
    int* rowstart = (int*)alloc((size_t)(NA + 1) * 4);
    int* cursor   = (int*)alloc((size_t)NA * 4);
    int* esrc     = (int*)alloc((size_t)NE * 4);
    int* bsum     = (int*)alloc(512 * 4);
    int* ms       = (int*)alloc((NMOL + 1) * 4);

    unsigned short* BTin = BTall;
    unsigned short* BT1[3], *BT2[3];
    for (int d = 0; d < 3; ++d) {
        BT1[d] = BTall + 256 * KIN + (size_t)(2 * d) * 65536;
        BT2[d] = BTall + 256 * KIN + (size_t)(2 * d + 1) * 65536;
    }

    const int* esrcIn = edge;        // edge_index[0] = src
    const int* edst   = edge + NE;   // edge_index[1] = dst

    zero_k<<<(NA + 255) / 256, 256, 0, stream>>>(counts, stSum, rowstart);
    prep_all_k<<<(256 * KIN + 6 * 65536 + 255) / 256, 256, 0, stream>>>(W_in_w, w1, w2, BTall);

    hist_k<<<(NE + 255) / 256, 256, 0, stream>>>(edst, counts);
    scan1_k<<<391, 256, 0, stream>>>(counts, rowstart, bsum);
    scan2_k<<<1, 512, 0, stream>>>(bsum, 391);
    scan3_k<<<391, 256, 0, stream>>>(rowstart, bsum, cursor);
    fill_k<<<(NE + 255) / 256, 256, 0, stream>>>(esrcIn, edst, cursor, esrc);
    molstart_k<<<(NMOL + 256) / 256, 256, 0, stream>>>(seg, ms);

    // x = relu(f_atoms @ W_in + b_in)
    gemm_k<true, false, true, false><<<dim3(2, (NA + 127) / 128), 256, 0, stream>>>(
        f_atoms, BTin, W_in_b, nullptr, nullptr, X, nullptr, nullptr, NA, KIN);

    for (int d = 0; d < 3; ++d) {
        if (d == 0)
            agg_k<false><<<NA / 4, 256, 0, stream>>>(X, nullptr, nullptr,
                rowstart, esrc, epsArr, d, AGG);
        else
            agg_k<true><<<NA / 4, 256, 0, stream>>>(X, sc2, sh2,
                rowstart, esrc, epsArr, d, AGG);
        // T1 = AGG @ w1 + b1 (+fused stats)
        gemm_k<false, false, false, true><<<dim3(2, (NA + 127) / 128), 256, 0, stream>>>(
            AGG, BT1[d], b1 + d * 256, nullptr, nullptr, T1, stSum, stSq, NA, 256);
        bnfin_k<<<1, 256, 0, stream>>>(stSum, stSq, g1 + d * 256, be1 + d * 256, sc1, sh1);
        // X = relu(BN(T1)) @ w2 + b2 (+fused stats)
        gemm_k<false, true, false, true><<<dim3(2, (NA + 127) / 128), 256, 0, stream>>>(
            T1, BT2[d], b2 + d * 256, sc1, sh1, X, stSum, stSq, NA, 256);
        bnfin_k<<<1, 256, 0, stream>>>(stSum, stSq, g2 + d * 256, be2 + d * 256, sc2, sh2);
    }

    mean_k<<<NMOL, 64, 0, stream>>>(X, sc2, sh2, ms, out);
}